// Round 10
// baseline (396.794 us; speedup 1.0000x reference)
//
#include <hip/hip_runtime.h>
#include <math.h>

#define H 64
#define NCONV 3
#define NGRAPHS 64
#define NCLASSES 10
#define TBL 8192
#define TROWS (TBL + 1)

typedef unsigned short bfu;

__device__ __forceinline__ float bf2f(bfu u) {
    return __uint_as_float(((unsigned int)u) << 16);
}
__device__ __forceinline__ bfu f2bf(float f) {
    unsigned int x = __float_as_uint(f);
    return (bfu)((x + 0x7FFF + ((x >> 16) & 1)) >> 16);
}
__device__ __forceinline__ float softplus_f(float x) {
    return fmaxf(x, 0.f) + log1pf(expf(-fabsf(x)));
}
__device__ __forceinline__ float bflo(unsigned int u) { return __uint_as_float(u << 16); }
__device__ __forceinline__ float bfhi(unsigned int u) { return __uint_as_float(u & 0xFFFF0000u); }

// packed edge record: bits 0-16 = src, bits 17-30 = quantized d index
__device__ __forceinline__ unsigned int ld_rec_nt(const unsigned int* p) {
    return __builtin_nontemporal_load(p);
}
#define REC_SRC(u) ((u) & 0x1FFFFu)
#define REC_T(u)   ((u) >> 17)

// ---------------- table build: tabs[4][TROWS][H] in bf16 -------------------
__global__ void build_tables(const float* __restrict__ W_emb1, const float* __restrict__ b_emb1,
                             const float* __restrict__ W_emb2, const float* __restrict__ b_emb2,
                             const float* __restrict__ fW1, const float* __restrict__ fb1,
                             const float* __restrict__ fW2, const float* __restrict__ fb2,
                             bfu* __restrict__ tabs)
{
    int which = blockIdx.y;
    const float *W1, *b1, *W2, *b2;
    if (which == 0) { W1 = W_emb1; b1 = b_emb1; W2 = W_emb2; b2 = b_emb2; }
    else {
        int l = which - 1;
        W1 = fW1 + l * H * H; b1 = fb1 + l * H;
        W2 = fW2 + l * H * H; b2 = fb2 + l * H;
    }

    __shared__ float sW1[H * H], sW2[H * H];
    __shared__ float sb1[H], sb2[H];
    __shared__ float sha[4][H], shb[4][H];

    int tid = threadIdx.x;
    for (int i = tid; i < H * H; i += 256) { sW1[i] = W1[i]; sW2[i] = W2[i]; }
    if (tid < H) sb1[tid] = b1[tid];
    else if (tid < 2 * H) sb2[tid - H] = b2[tid - H];
    __syncthreads();

    int wave = tid >> 6, lane = tid & 63;
    int base = blockIdx.x * 64;
    int lim  = min(base + 64, TROWS);

    for (int r = base + wave; r < lim; r += 4) {
        float dv   = (float)r / (float)TBL;
        float mu   = (float)lane / (float)(H - 1);
        float diff = dv - mu;
        float cut  = 0.5f * (cosf(3.14159265358979323846f * dv) + 1.0f);
        float bfj  = expf(-(float)H * diff * diff) * cut;

        sha[wave][lane] = bfj;
        float a = sb1[lane];
        #pragma unroll
        for (int i = 0; i < H; ++i) a = fmaf(sha[wave][i], sW1[i * H + lane], a);
        shb[wave][lane] = softplus_f(a);
        float a2 = sb2[lane];
        #pragma unroll
        for (int i = 0; i < H; ++i) a2 = fmaf(shb[wave][i], sW2[i * H + lane], a2);

        tabs[((size_t)which * TROWS + r) * H + lane] = f2bf(a2);
    }
}

// ---------------- CSR build (group edges by dst) -------------------
// 8 edges per thread, grid-stride: 8 independent atomics in flight per lane.
#define HU 8
__global__ void hist_rank(const int* __restrict__ dst, int* __restrict__ cnt,
                          int* __restrict__ rank, int E) {
    int tid    = blockIdx.x * blockDim.x + threadIdx.x;
    int stride = gridDim.x * blockDim.x;
    int e[HU];
    int d[HU];
    int r[HU];
    #pragma unroll
    for (int k = 0; k < HU; ++k) e[k] = tid + k * stride;
    #pragma unroll
    for (int k = 0; k < HU; ++k) if (e[k] < E) d[k] = dst[e[k]];
    #pragma unroll
    for (int k = 0; k < HU; ++k) if (e[k] < E) r[k] = atomicAdd(&cnt[d[k]], 1);
    #pragma unroll
    for (int k = 0; k < HU; ++k) if (e[k] < E) rank[e[k]] = r[k];
}

__global__ void scan_bsum(const int* __restrict__ cnt, int* __restrict__ bsum, int N) {
    __shared__ int s[256];
    int t = threadIdx.x;
    int i = blockIdx.x * 256 + t;
    s[t] = (i < N) ? cnt[i] : 0;
    __syncthreads();
    for (int o = 128; o > 0; o >>= 1) {
        if (t < o) s[t] += s[t + o];
        __syncthreads();
    }
    if (t == 0) bsum[blockIdx.x] = s[0];
}

__global__ void scan_gsum(const int* __restrict__ bsum, int* __restrict__ gsum, int nblk) {
    __shared__ int s[1024];
    int t = threadIdx.x;
    s[t] = (t < nblk) ? bsum[t] : 0;
    __syncthreads();
    for (int o = 1; o < 1024; o <<= 1) {
        int v = (t >= o) ? s[t - o] : 0;
        __syncthreads();
        s[t] += v;
        __syncthreads();
    }
    if (t < nblk) gsum[t] = s[t] - bsum[t];   // exclusive prefix
}

__global__ void scan_off(const int* __restrict__ cnt, const int* __restrict__ gsum,
                         int* __restrict__ off, int N) {
    __shared__ int s[256];
    int t = threadIdx.x;
    int i = blockIdx.x * 256 + t;
    int v = (i < N) ? cnt[i] : 0;
    s[t] = v;
    __syncthreads();
    for (int o = 1; o < 256; o <<= 1) {
        int u = (t >= o) ? s[t - o] : 0;
        __syncthreads();
        s[t] += u;
        __syncthreads();
    }
    int incl = s[t] + gsum[blockIdx.x];
    if (i < N) {
        off[i] = incl - v;
        if (i == N - 1) off[N] = incl;
    }
}

// 4 edges per thread, grid-stride: batched independent loads/stores.
#define SU 4
__global__ void scatter_kernel(const int* __restrict__ src, const int* __restrict__ dst,
                               const float* __restrict__ d, const int* __restrict__ off,
                               const int* __restrict__ rank, unsigned int* __restrict__ recs, int E)
{
    int tid    = blockIdx.x * blockDim.x + threadIdx.x;
    int stride = gridDim.x * blockDim.x;
    int e[SU];
    int dv_[SU]; int rk[SU]; int sr[SU]; float dd[SU]; int ofv[SU];
    #pragma unroll
    for (int k = 0; k < SU; ++k) e[k] = tid + k * stride;
    #pragma unroll
    for (int k = 0; k < SU; ++k) if (e[k] < E) { dv_[k] = dst[e[k]]; rk[k] = rank[e[k]]; sr[k] = src[e[k]]; dd[k] = d[e[k]]; }
    #pragma unroll
    for (int k = 0; k < SU; ++k) if (e[k] < E) ofv[k] = off[dv_[k]];
    #pragma unroll
    for (int k = 0; k < SU; ++k) if (e[k] < E) {
        float dv = fminf(fmaxf(dd[k], 0.f), 1.f);
        int t = (int)(dv * (float)TBL + 0.5f);
        t = min(t, TBL);
        recs[ofv[k] + rk[k]] = (unsigned int)sr[k] | ((unsigned int)t << 17);
    }
}

// ---------------- embedding fused with W_in0 -------------------
// Half-wave contiguous split; 3-stage pipeline: recs(i+2) / values(i+1) / fma(i).
__global__ void emb_fused(const int* __restrict__ off, const unsigned int* __restrict__ recs,
                          const bfu* __restrict__ tab, const float* __restrict__ W,
                          const float* __restrict__ bvec, bfu* __restrict__ yout, int N)
{
    __shared__ float sW[H * H];
    __shared__ float sb[H];
    __shared__ float sx[4][H];
    int tid = threadIdx.x;
    for (int i = tid; i < H * H; i += 256) sW[i] = W[i];
    if (tid < H) sb[tid] = bvec[tid];
    __syncthreads();

    const unsigned int* tab32 = (const unsigned int*)tab;

    int wave = tid >> 6, lane = tid & 63;
    int half = lane >> 5;
    int li   = lane & 31;

    for (int k = 0; k < 4; ++k) {
        int node = blockIdx.x * 16 + k * 4 + wave;
        if (node >= N) continue;
        int b = off[node], en = off[node + 1];
        int deg = en - b;
        int c0  = (deg + 1) >> 1;
        int p   = b + half * c0;
        int e   = (half == 0) ? (b + c0) : en;

        float a0 = 0.f, a1 = 0.f, a2 = 0.f, a3 = 0.f;

        if (e - p >= 8) {
            unsigned int u0 = ld_rec_nt(recs + p);
            unsigned int u1 = ld_rec_nt(recs + p + 1);
            unsigned int u2 = ld_rec_nt(recs + p + 2);
            unsigned int u3 = ld_rec_nt(recs + p + 3);
            unsigned int tv0 = tab32[(size_t)REC_T(u0) * 32 + li];
            unsigned int tv1 = tab32[(size_t)REC_T(u1) * 32 + li];
            unsigned int tv2 = tab32[(size_t)REC_T(u2) * 32 + li];
            unsigned int tv3 = tab32[(size_t)REC_T(u3) * 32 + li];
            u0 = ld_rec_nt(recs + p + 4);
            u1 = ld_rec_nt(recs + p + 5);
            u2 = ld_rec_nt(recs + p + 6);
            u3 = ld_rec_nt(recs + p + 7);
            while (p + 12 <= e) {
                unsigned int w0 = ld_rec_nt(recs + p + 8);
                unsigned int w1 = ld_rec_nt(recs + p + 9);
                unsigned int w2 = ld_rec_nt(recs + p + 10);
                unsigned int w3 = ld_rec_nt(recs + p + 11);
                unsigned int n0 = tab32[(size_t)REC_T(u0) * 32 + li];
                unsigned int n1 = tab32[(size_t)REC_T(u1) * 32 + li];
                unsigned int n2 = tab32[(size_t)REC_T(u2) * 32 + li];
                unsigned int n3 = tab32[(size_t)REC_T(u3) * 32 + li];
                a0 += bflo(tv0); a1 += bfhi(tv0);
                a2 += bflo(tv1); a3 += bfhi(tv1);
                a0 += bflo(tv2); a1 += bfhi(tv2);
                a2 += bflo(tv3); a3 += bfhi(tv3);
                tv0 = n0; tv1 = n1; tv2 = n2; tv3 = n3;
                u0 = w0; u1 = w1; u2 = w2; u3 = w3;
                p += 4;
            }
            // drain: values in tv (edges p..p+3), recs in u (edges p+4..p+7)
            unsigned int n0 = tab32[(size_t)REC_T(u0) * 32 + li];
            unsigned int n1 = tab32[(size_t)REC_T(u1) * 32 + li];
            unsigned int n2 = tab32[(size_t)REC_T(u2) * 32 + li];
            unsigned int n3 = tab32[(size_t)REC_T(u3) * 32 + li];
            a0 += bflo(tv0); a1 += bfhi(tv0);
            a2 += bflo(tv1); a3 += bfhi(tv1);
            a0 += bflo(tv2); a1 += bfhi(tv2);
            a2 += bflo(tv3); a3 += bfhi(tv3);
            a0 += bflo(n0); a1 += bfhi(n0);
            a2 += bflo(n1); a3 += bfhi(n1);
            a0 += bflo(n2); a1 += bfhi(n2);
            a2 += bflo(n3); a3 += bfhi(n3);
            p += 8;
        } else if (e - p >= 4) {
            unsigned int u0 = ld_rec_nt(recs + p);
            unsigned int u1 = ld_rec_nt(recs + p + 1);
            unsigned int u2 = ld_rec_nt(recs + p + 2);
            unsigned int u3 = ld_rec_nt(recs + p + 3);
            unsigned int n0 = tab32[(size_t)REC_T(u0) * 32 + li];
            unsigned int n1 = tab32[(size_t)REC_T(u1) * 32 + li];
            unsigned int n2 = tab32[(size_t)REC_T(u2) * 32 + li];
            unsigned int n3 = tab32[(size_t)REC_T(u3) * 32 + li];
            a0 += bflo(n0); a1 += bfhi(n0);
            a2 += bflo(n1); a3 += bfhi(n1);
            a0 += bflo(n2); a1 += bfhi(n2);
            a2 += bflo(n3); a3 += bfhi(n3);
            p += 4;
        }
        for (; p < e; ++p) {
            unsigned int u = ld_rec_nt(recs + p);
            unsigned int t = tab32[(size_t)REC_T(u) * 32 + li];
            a0 += bflo(t); a1 += bfhi(t);
        }

        float alo = a0 + a2, ahi = a1 + a3;
        alo += __shfl_down(alo, 32);
        ahi += __shfl_down(ahi, 32);
        if (lane < 32) {
            sx[wave][2 * li]     = alo;
            sx[wave][2 * li + 1] = ahi;
        }
        float o = sb[lane];
        #pragma unroll
        for (int i = 0; i < H; ++i) o = fmaf(sx[wave][i], sW[i * H + lane], o);
        yout[(size_t)node * H + lane] = f2bf(o);
    }
}

// ---------------- conv layer -------------------
// agg = sum_e filt_tab[t_e] * y[src_e];  out = relu(agg @ W_out + b_out)
// Half-wave contiguous split; 3-stage pipeline: recs(i+2)/values(i+1)/fma(i).
template <bool LAST>
__global__ void conv_fused_k(const int* __restrict__ off, const unsigned int* __restrict__ recs,
                             const bfu* __restrict__ tab, const bfu* __restrict__ y,
                             const float* __restrict__ W_out, const float* __restrict__ b_out,
                             bfu* __restrict__ yout, float* __restrict__ xout, int N)
{
    __shared__ float sW[H * H];
    __shared__ float sb[H];
    __shared__ float sx[4][H];
    int tid = threadIdx.x;
    for (int i = tid; i < H * H; i += 256) sW[i] = W_out[i];
    if (tid < H) sb[tid] = b_out[tid];
    __syncthreads();

    const unsigned int* tab32 = (const unsigned int*)tab;
    const unsigned int* y32   = (const unsigned int*)y;

    int wave = tid >> 6, lane = tid & 63;
    int half = lane >> 5;
    int li   = lane & 31;

    for (int k = 0; k < 4; ++k) {
        int node = blockIdx.x * 16 + k * 4 + wave;
        if (node >= N) continue;
        int b = off[node], en = off[node + 1];
        int deg = en - b;
        int c0  = (deg + 1) >> 1;
        int p   = b + half * c0;
        int e   = (half == 0) ? (b + c0) : en;

        float a0 = 0.f, a1 = 0.f, a2 = 0.f, a3 = 0.f;

        if (e - p >= 8) {
            unsigned int u0 = ld_rec_nt(recs + p);
            unsigned int u1 = ld_rec_nt(recs + p + 1);
            unsigned int u2 = ld_rec_nt(recs + p + 2);
            unsigned int u3 = ld_rec_nt(recs + p + 3);
            unsigned int tv0 = tab32[(size_t)REC_T(u0) * 32 + li];
            unsigned int yv0 = y32[(size_t)REC_SRC(u0) * 32 + li];
            unsigned int tv1 = tab32[(size_t)REC_T(u1) * 32 + li];
            unsigned int yv1 = y32[(size_t)REC_SRC(u1) * 32 + li];
            unsigned int tv2 = tab32[(size_t)REC_T(u2) * 32 + li];
            unsigned int yv2 = y32[(size_t)REC_SRC(u2) * 32 + li];
            unsigned int tv3 = tab32[(size_t)REC_T(u3) * 32 + li];
            unsigned int yv3 = y32[(size_t)REC_SRC(u3) * 32 + li];
            u0 = ld_rec_nt(recs + p + 4);
            u1 = ld_rec_nt(recs + p + 5);
            u2 = ld_rec_nt(recs + p + 6);
            u3 = ld_rec_nt(recs + p + 7);
            while (p + 12 <= e) {
                unsigned int w0 = ld_rec_nt(recs + p + 8);
                unsigned int w1 = ld_rec_nt(recs + p + 9);
                unsigned int w2 = ld_rec_nt(recs + p + 10);
                unsigned int w3 = ld_rec_nt(recs + p + 11);
                unsigned int nt0 = tab32[(size_t)REC_T(u0) * 32 + li];
                unsigned int ny0 = y32[(size_t)REC_SRC(u0) * 32 + li];
                unsigned int nt1 = tab32[(size_t)REC_T(u1) * 32 + li];
                unsigned int ny1 = y32[(size_t)REC_SRC(u1) * 32 + li];
                unsigned int nt2 = tab32[(size_t)REC_T(u2) * 32 + li];
                unsigned int ny2 = y32[(size_t)REC_SRC(u2) * 32 + li];
                unsigned int nt3 = tab32[(size_t)REC_T(u3) * 32 + li];
                unsigned int ny3 = y32[(size_t)REC_SRC(u3) * 32 + li];
                a0 = fmaf(bflo(yv0), bflo(tv0), a0);
                a1 = fmaf(bfhi(yv0), bfhi(tv0), a1);
                a2 = fmaf(bflo(yv1), bflo(tv1), a2);
                a3 = fmaf(bfhi(yv1), bfhi(tv1), a3);
                a0 = fmaf(bflo(yv2), bflo(tv2), a0);
                a1 = fmaf(bfhi(yv2), bfhi(tv2), a1);
                a2 = fmaf(bflo(yv3), bflo(tv3), a2);
                a3 = fmaf(bfhi(yv3), bfhi(tv3), a3);
                tv0 = nt0; yv0 = ny0; tv1 = nt1; yv1 = ny1;
                tv2 = nt2; yv2 = ny2; tv3 = nt3; yv3 = ny3;
                u0 = w0; u1 = w1; u2 = w2; u3 = w3;
                p += 4;
            }
            // drain: values in tv/yv (p..p+3), recs in u (p+4..p+7)
            unsigned int nt0 = tab32[(size_t)REC_T(u0) * 32 + li];
            unsigned int ny0 = y32[(size_t)REC_SRC(u0) * 32 + li];
            unsigned int nt1 = tab32[(size_t)REC_T(u1) * 32 + li];
            unsigned int ny1 = y32[(size_t)REC_SRC(u1) * 32 + li];
            unsigned int nt2 = tab32[(size_t)REC_T(u2) * 32 + li];
            unsigned int ny2 = y32[(size_t)REC_SRC(u2) * 32 + li];
            unsigned int nt3 = tab32[(size_t)REC_T(u3) * 32 + li];
            unsigned int ny3 = y32[(size_t)REC_SRC(u3) * 32 + li];
            a0 = fmaf(bflo(yv0), bflo(tv0), a0);
            a1 = fmaf(bfhi(yv0), bfhi(tv0), a1);
            a2 = fmaf(bflo(yv1), bflo(tv1), a2);
            a3 = fmaf(bfhi(yv1), bfhi(tv1), a3);
            a0 = fmaf(bflo(yv2), bflo(tv2), a0);
            a1 = fmaf(bfhi(yv2), bfhi(tv2), a1);
            a2 = fmaf(bflo(yv3), bflo(tv3), a2);
            a3 = fmaf(bfhi(yv3), bfhi(tv3), a3);
            a0 = fmaf(bflo(ny0), bflo(nt0), a0);
            a1 = fmaf(bfhi(ny0), bfhi(nt0), a1);
            a2 = fmaf(bflo(ny1), bflo(nt1), a2);
            a3 = fmaf(bfhi(ny1), bfhi(nt1), a3);
            a0 = fmaf(bflo(ny2), bflo(nt2), a0);
            a1 = fmaf(bfhi(ny2), bfhi(nt2), a1);
            a2 = fmaf(bflo(ny3), bflo(nt3), a2);
            a3 = fmaf(bfhi(ny3), bfhi(nt3), a3);
            p += 8;
        } else if (e - p >= 4) {
            unsigned int u0 = ld_rec_nt(recs + p);
            unsigned int u1 = ld_rec_nt(recs + p + 1);
            unsigned int u2 = ld_rec_nt(recs + p + 2);
            unsigned int u3 = ld_rec_nt(recs + p + 3);
            unsigned int nt0 = tab32[(size_t)REC_T(u0) * 32 + li];
            unsigned int ny0 = y32[(size_t)REC_SRC(u0) * 32 + li];
            unsigned int nt1 = tab32[(size_t)REC_T(u1) * 32 + li];
            unsigned int ny1 = y32[(size_t)REC_SRC(u1) * 32 + li];
            unsigned int nt2 = tab32[(size_t)REC_T(u2) * 32 + li];
            unsigned int ny2 = y32[(size_t)REC_SRC(u2) * 32 + li];
            unsigned int nt3 = tab32[(size_t)REC_T(u3) * 32 + li];
            unsigned int ny3 = y32[(size_t)REC_SRC(u3) * 32 + li];
            a0 = fmaf(bflo(ny0), bflo(nt0), a0);
            a1 = fmaf(bfhi(ny0), bfhi(nt0), a1);
            a2 = fmaf(bflo(ny1), bflo(nt1), a2);
            a3 = fmaf(bfhi(ny1), bfhi(nt1), a3);
            a0 = fmaf(bflo(ny2), bflo(nt2), a0);
            a1 = fmaf(bfhi(ny2), bfhi(nt2), a1);
            a2 = fmaf(bflo(ny3), bflo(nt3), a2);
            a3 = fmaf(bfhi(ny3), bfhi(nt3), a3);
            p += 4;
        }
        for (; p < e; ++p) {
            unsigned int u = ld_rec_nt(recs + p);
            unsigned int t = tab32[(size_t)REC_T(u) * 32 + li];
            unsigned int v = y32[(size_t)REC_SRC(u) * 32 + li];
            a0 = fmaf(bflo(v), bflo(t), a0);
            a1 = fmaf(bfhi(v), bfhi(t), a1);
        }

        float alo = a0 + a2, ahi = a1 + a3;
        alo += __shfl_down(alo, 32);
        ahi += __shfl_down(ahi, 32);
        if (lane < 32) {
            sx[wave][2 * li]     = alo;
            sx[wave][2 * li + 1] = ahi;
        }
        float o = sb[lane];
        #pragma unroll
        for (int i = 0; i < H; ++i) o = fmaf(sx[wave][i], sW[i * H + lane], o);
        o = fmaxf(o, 0.f);
        if (LAST) xout[(size_t)node * H + lane] = o;
        else      yout[(size_t)node * H + lane] = f2bf(o);
    }
}

// ---------------- node projection: y = x @ W + b (bf16 in/out) -------------
__global__ void node_proj(const bfu* __restrict__ xin, const float* __restrict__ W,
                          const float* __restrict__ bvec, bfu* __restrict__ yout, int N)
{
    __shared__ float sW[H * H];
    __shared__ float sb[H];
    __shared__ float sx[4][H];
    int tid = threadIdx.x;
    for (int i = tid; i < H * H; i += 256) sW[i] = W[i];
    if (tid < H) sb[tid] = bvec[tid];
    __syncthreads();

    int wave = tid >> 6, lane = tid & 63;
    for (int k = 0; k < 4; ++k) {
        int node = blockIdx.x * 16 + k * 4 + wave;
        if (node >= N) continue;
        sx[wave][lane] = bf2f(xin[(size_t)node * H + lane]);
        float o = sb[lane];
        #pragma unroll
        for (int i = 0; i < H; ++i) o = fmaf(sx[wave][i], sW[i * H + lane], o);
        yout[(size_t)node * H + lane] = f2bf(o);
    }
}

// ---------------- pooling (sorted gid, run-length flush) -------------------
__global__ void pool_kernel(const float* __restrict__ x, const int* __restrict__ gid,
                            float* __restrict__ pooled, float* __restrict__ counts, int N)
{
    int wavesPerBlock = blockDim.x >> 6;
    int wid  = blockIdx.x * wavesPerBlock + (threadIdx.x >> 6);
    int lane = threadIdx.x & 63;
    int totalWaves = gridDim.x * wavesPerBlock;
    int chunk = (N + totalWaves - 1) / totalWaves;
    int beg = wid * chunk, end = min(beg + chunk, N);
    if (beg >= end) return;

    float acc = 0.f;
    int cur = -1, cnt = 0;
    for (int n = beg; n < end; ++n) {
        int g = gid[n];
        if (g != cur) {
            if (cur >= 0) {
                atomicAdd(&pooled[(size_t)cur * H + lane], acc);
                if (lane == 0) atomicAdd(&counts[cur], (float)cnt);
            }
            cur = g; acc = 0.f; cnt = 0;
        }
        acc += x[(size_t)n * H + lane];
        cnt++;
    }
    atomicAdd(&pooled[(size_t)cur * H + lane], acc);
    if (lane == 0) atomicAdd(&counts[cur], (float)cnt);
}

// ---------------- head -------------------
__global__ void head_kernel(const float* __restrict__ pooled, const float* __restrict__ counts,
                            const float* __restrict__ Wfc, const float* __restrict__ bfc,
                            float* __restrict__ out)
{
    int g = blockIdx.x;
    int c = threadIdx.x;
    __shared__ float logits[NCLASSES];
    float cnt = fmaxf(counts[g], 1.0f);
    if (c < NCLASSES) {
        float acc = bfc[c];
        #pragma unroll
        for (int i = 0; i < H; ++i)
            acc = fmaf(pooled[(size_t)g * H + i] / cnt, Wfc[i * NCLASSES + c], acc);
        logits[c] = acc;
    }
    __syncthreads();
    if (c < NCLASSES) {
        float m = -INFINITY;
        #pragma unroll
        for (int k = 0; k < NCLASSES; ++k) m = fmaxf(m, logits[k]);
        float s = 0.f;
        #pragma unroll
        for (int k = 0; k < NCLASSES; ++k) s += expf(logits[k] - m);
        out[g * NCLASSES + c] = logits[c] - m - logf(s);
    }
}

extern "C" void kernel_launch(void* const* d_in, const int* in_sizes, int n_in,
                              void* d_out, int out_size, void* d_ws, size_t ws_size,
                              hipStream_t stream)
{
    const float* d_d    = (const float*)d_in[0];
    const float* W_emb1 = (const float*)d_in[1];
    const float* b_emb1 = (const float*)d_in[2];
    const float* W_emb2 = (const float*)d_in[3];
    const float* b_emb2 = (const float*)d_in[4];
    const float* fW1    = (const float*)d_in[5];
    const float* fb1    = (const float*)d_in[6];
    const float* fW2    = (const float*)d_in[7];
    const float* fb2    = (const float*)d_in[8];
    const float* W_in   = (const float*)d_in[9];
    const float* b_in   = (const float*)d_in[10];
    const float* W_out  = (const float*)d_in[11];
    const float* b_out  = (const float*)d_in[12];
    const float* W_fc   = (const float*)d_in[13];
    const float* b_fc   = (const float*)d_in[14];
    const int*   src    = (const int*)d_in[15];
    const int*   dst    = (const int*)d_in[16];
    const int*   gid    = (const int*)d_in[17];

    const int E = in_sizes[0];
    const int N = in_sizes[17];

    float* out = (float*)d_out;

    // workspace layout
    char* base = (char*)d_ws;
    unsigned int* recs = (unsigned int*)base;   base += (size_t)E * 4;
    int*  rank   = (int*)base;                  base += (size_t)E * 4;
    bfu*  tabs   = (bfu*)base;                  base += (size_t)4 * TROWS * H * 2;
    bfu*  yA     = (bfu*)base;                  base += (size_t)N * H * 2;
    bfu*  xB     = (bfu*)base;                  base += (size_t)N * H * 2;
    float* x3    = (float*)base;                base += (size_t)N * H * 4;
    float* pooled= (float*)base;                base += (size_t)NGRAPHS * H * 4;
    float* counts= (float*)base;                base += (size_t)NGRAPHS * 4;
    int*  cnt    = (int*)base;                  base += (size_t)N * 4;
    int*  off    = (int*)base;                  base += (size_t)(N + 1) * 4;
    int*  bsum   = (int*)base;                  base += (size_t)1024 * 4;
    int*  gsum   = (int*)base;                  base += (size_t)1024 * 4;

    const int node_blocks16 = (N + 15) / 16;
    const int scan_blocks   = (N + 255) / 256;   // must be <= 1024
    const int hist_blocks   = (E + 256 * HU - 1) / (256 * HU);
    const int scat_blocks   = (E + 256 * SU - 1) / (256 * SU);

    // 1. bf16 MLP lookup tables
    dim3 tg((TROWS + 63) / 64, 4);
    build_tables<<<tg, 256, 0, stream>>>(W_emb1, b_emb1, W_emb2, b_emb2,
                                         fW1, fb1, fW2, fb2, tabs);

    // 2. CSR build: hist+rank (8/thread), 3-phase scan, atomic-free scatter (4/thread)
    hipMemsetAsync(cnt, 0, (size_t)N * 4, stream);
    hist_rank<<<hist_blocks, 256, 0, stream>>>(dst, cnt, rank, E);
    scan_bsum<<<scan_blocks, 256, 0, stream>>>(cnt, bsum, N);
    scan_gsum<<<1, 1024, 0, stream>>>(bsum, gsum, scan_blocks);
    scan_off<<<scan_blocks, 256, 0, stream>>>(cnt, gsum, off, N);
    scatter_kernel<<<scat_blocks, 256, 0, stream>>>(src, dst, d_d, off, rank, recs, E);

    // 3. embedding + W_in0 -> yA
    emb_fused<<<node_blocks16, 256, 0, stream>>>(off, recs, tabs, W_in, b_in, yA, N);

    // 4. conv layers (conv writes xB; proj writes yA)
    conv_fused_k<false><<<node_blocks16, 256, 0, stream>>>(
        off, recs, tabs + (size_t)1 * TROWS * H, yA, W_out, b_out, xB, nullptr, N);
    node_proj<<<node_blocks16, 256, 0, stream>>>(
        xB, W_in + (size_t)1 * H * H, b_in + (size_t)1 * H, yA, N);

    conv_fused_k<false><<<node_blocks16, 256, 0, stream>>>(
        off, recs, tabs + (size_t)2 * TROWS * H, yA,
        W_out + (size_t)1 * H * H, b_out + (size_t)1 * H, xB, nullptr, N);
    node_proj<<<node_blocks16, 256, 0, stream>>>(
        xB, W_in + (size_t)2 * H * H, b_in + (size_t)2 * H, yA, N);

    conv_fused_k<true><<<node_blocks16, 256, 0, stream>>>(
        off, recs, tabs + (size_t)3 * TROWS * H, yA,
        W_out + (size_t)2 * H * H, b_out + (size_t)2 * H, nullptr, x3, N);

    // 5. pooling
    hipMemsetAsync(pooled, 0, ((size_t)NGRAPHS * H + NGRAPHS) * 4, stream);
    pool_kernel<<<128, 256, 0, stream>>>(x3, gid, pooled, counts, N);

    // 6. head
    head_kernel<<<NGRAPHS, 64, 0, stream>>>(pooled, counts, W_fc, b_fc, out);
}

// Round 11
// 321.576 us; speedup vs baseline: 1.2339x; 1.2339x over previous
//
#include <hip/hip_runtime.h>
#include <math.h>

#define H 64
#define NCONV 3
#define NGRAPHS 64
#define NCLASSES 10
#define TBL 8192
#define TROWS (TBL + 1)
#define CAP 6144          // coarse-bucket capacity: mean 4704 + ~21 sigma
#define EPT 8             // edges/thread in coarse_part

typedef unsigned short bfu;

__device__ __forceinline__ float bf2f(bfu u) {
    return __uint_as_float(((unsigned int)u) << 16);
}
__device__ __forceinline__ bfu f2bf(float f) {
    unsigned int x = __float_as_uint(f);
    return (bfu)((x + 0x7FFF + ((x >> 16) & 1)) >> 16);
}
__device__ __forceinline__ float softplus_f(float x) {
    return fmaxf(x, 0.f) + log1pf(expf(-fabsf(x)));
}
__device__ __forceinline__ float bflo(unsigned int u) { return __uint_as_float(u << 16); }
__device__ __forceinline__ float bfhi(unsigned int u) { return __uint_as_float(u & 0xFFFF0000u); }

// packed edge record: bits 0-16 = src, bits 17-30 = quantized d index
__device__ __forceinline__ unsigned int ld_rec_nt(const unsigned int* p) {
    return __builtin_nontemporal_load(p);
}
#define REC_SRC(u) ((u) & 0x1FFFFu)
#define REC_T(u)   ((u) >> 17)

// ---------------- table build: tabs[4][TROWS][H] in bf16 -------------------
__global__ void build_tables(const float* __restrict__ W_emb1, const float* __restrict__ b_emb1,
                             const float* __restrict__ W_emb2, const float* __restrict__ b_emb2,
                             const float* __restrict__ fW1, const float* __restrict__ fb1,
                             const float* __restrict__ fW2, const float* __restrict__ fb2,
                             bfu* __restrict__ tabs)
{
    int which = blockIdx.y;
    const float *W1, *b1, *W2, *b2;
    if (which == 0) { W1 = W_emb1; b1 = b_emb1; W2 = W_emb2; b2 = b_emb2; }
    else {
        int l = which - 1;
        W1 = fW1 + l * H * H; b1 = fb1 + l * H;
        W2 = fW2 + l * H * H; b2 = fb2 + l * H;
    }

    __shared__ float sW1[H * H], sW2[H * H];
    __shared__ float sb1[H], sb2[H];
    __shared__ float sha[4][H], shb[4][H];

    int tid = threadIdx.x;
    for (int i = tid; i < H * H; i += 256) { sW1[i] = W1[i]; sW2[i] = W2[i]; }
    if (tid < H) sb1[tid] = b1[tid];
    else if (tid < 2 * H) sb2[tid - H] = b2[tid - H];
    __syncthreads();

    int wave = tid >> 6, lane = tid & 63;
    int base = blockIdx.x * 64;
    int lim  = min(base + 64, TROWS);

    for (int r = base + wave; r < lim; r += 4) {
        float dv   = (float)r / (float)TBL;
        float mu   = (float)lane / (float)(H - 1);
        float diff = dv - mu;
        float cut  = 0.5f * (cosf(3.14159265358979323846f * dv) + 1.0f);
        float bfj  = expf(-(float)H * diff * diff) * cut;

        sha[wave][lane] = bfj;
        float a = sb1[lane];
        #pragma unroll
        for (int i = 0; i < H; ++i) a = fmaf(sha[wave][i], sW1[i * H + lane], a);
        shb[wave][lane] = softplus_f(a);
        float a2 = sb2[lane];
        #pragma unroll
        for (int i = 0; i < H; ++i) a2 = fmaf(shb[wave][i], sW2[i * H + lane], a2);

        tabs[((size_t)which * TROWS + r) * H + lane] = f2bf(a2);
    }
}

// ---------------- CSR build: two-level LDS counting sort -------------------
__global__ void coarse_part(const int* __restrict__ src, const int* __restrict__ dst,
                            const float* __restrict__ d, int* __restrict__ ccur,
                            unsigned long long* __restrict__ cbuf, int E, int ncb)
{
    __shared__ int lcnt[256];
    __shared__ int lbase[256];
    int tid = threadIdx.x;
    int e0  = blockIdx.x * (256 * EPT);

    lcnt[tid] = 0;
    __syncthreads();

    int mybin[EPT], myrank[EPT];
    unsigned long long myrec[EPT];
    #pragma unroll
    for (int k = 0; k < EPT; ++k) {
        int e = e0 + k * 256 + tid;
        mybin[k] = -1;
        if (e < E) {
            int v = dst[e];
            int bin = v >> 8;
            float dv = fminf(fmaxf(d[e], 0.f), 1.f);
            int t = (int)(dv * (float)TBL + 0.5f);
            t = min(t, TBL);
            unsigned int p31 = (unsigned int)src[e] | ((unsigned int)t << 17);
            myrec[k]  = (unsigned long long)p31 | ((unsigned long long)(v & 255) << 32);
            mybin[k]  = bin;
            myrank[k] = atomicAdd(&lcnt[bin], 1);
        }
    }
    __syncthreads();

    {
        int c = (tid < ncb) ? lcnt[tid] : 0;
        lbase[tid] = (c > 0) ? atomicAdd(&ccur[tid], c) : 0;
    }
    __syncthreads();

    #pragma unroll
    for (int k = 0; k < EPT; ++k) {
        if (mybin[k] >= 0) {
            cbuf[(size_t)mybin[k] * CAP + lbase[mybin[k]] + myrank[k]] = myrec[k];
        }
    }
}

__global__ void cscan(const int* __restrict__ ccur, int* __restrict__ cstart,
                      int* __restrict__ off, int E, int N, int ncb)
{
    __shared__ int s[256];
    int t = threadIdx.x;
    int v = (t < ncb) ? ccur[t] : 0;
    s[t] = v;
    __syncthreads();
    for (int o = 1; o < 256; o <<= 1) {
        int u = (t >= o) ? s[t - o] : 0;
        __syncthreads();
        s[t] += u;
        __syncthreads();
    }
    if (t < ncb) cstart[t] = s[t] - v;
    if (t == 0) off[N] = E;
}

__global__ void fine_sort(const unsigned long long* __restrict__ cbuf,
                          const int* __restrict__ ccur, const int* __restrict__ cstart,
                          int* __restrict__ off, unsigned int* __restrict__ recs, int N)
{
    __shared__ int lcnt[256];
    __shared__ int ss[256];
    __shared__ int lcur[256];
    int bin  = blockIdx.x;
    int tid  = threadIdx.x;
    int cnt  = ccur[bin];
    int base = cstart[bin];
    const unsigned long long* buf = cbuf + (size_t)bin * CAP;

    lcnt[tid] = 0;
    __syncthreads();
    for (int i = tid; i < cnt; i += 256) {
        int j = (int)((buf[i] >> 32) & 255);
        atomicAdd(&lcnt[j], 1);
    }
    __syncthreads();
    int v = lcnt[tid];
    ss[tid] = v;
    __syncthreads();
    for (int o = 1; o < 256; o <<= 1) {
        int u = (tid >= o) ? ss[tid - o] : 0;
        __syncthreads();
        ss[tid] += u;
        __syncthreads();
    }
    int excl = ss[tid] - v;
    lcur[tid] = excl;
    int node = bin * 256 + tid;
    if (node < N) off[node] = base + excl;
    __syncthreads();
    for (int i = tid; i < cnt; i += 256) {
        unsigned long long r = buf[i];
        int j = (int)((r >> 32) & 255);
        int pos = base + atomicAdd(&lcur[j], 1);
        recs[pos] = (unsigned int)(r & 0x7FFFFFFFu);
    }
}

// ---------------- embedding fused with W_in0 -------------------
__global__ void emb_fused(const int* __restrict__ off, const unsigned int* __restrict__ recs,
                          const bfu* __restrict__ tab, const float* __restrict__ W,
                          const float* __restrict__ bvec, bfu* __restrict__ yout, int N)
{
    __shared__ float sW[H * H];
    __shared__ float sb[H];
    __shared__ float sx[4][H];
    int tid = threadIdx.x;
    for (int i = tid; i < H * H; i += 256) sW[i] = W[i];
    if (tid < H) sb[tid] = bvec[tid];
    __syncthreads();

    const unsigned int* tab32 = (const unsigned int*)tab;

    int wave = tid >> 6, lane = tid & 63;
    int half = lane >> 5;
    int li   = lane & 31;

    for (int k = 0; k < 4; ++k) {
        int node = blockIdx.x * 16 + k * 4 + wave;
        if (node >= N) continue;
        int b = off[node], en = off[node + 1];
        int deg = en - b;
        int c0  = (deg + 1) >> 1;
        int p   = b + half * c0;
        int e   = (half == 0) ? (b + c0) : en;

        float a0 = 0.f, a1 = 0.f, a2 = 0.f, a3 = 0.f;

        if (e - p >= 8) {
            unsigned int u0 = ld_rec_nt(recs + p);
            unsigned int u1 = ld_rec_nt(recs + p + 1);
            unsigned int u2 = ld_rec_nt(recs + p + 2);
            unsigned int u3 = ld_rec_nt(recs + p + 3);
            unsigned int tv0 = tab32[(size_t)REC_T(u0) * 32 + li];
            unsigned int tv1 = tab32[(size_t)REC_T(u1) * 32 + li];
            unsigned int tv2 = tab32[(size_t)REC_T(u2) * 32 + li];
            unsigned int tv3 = tab32[(size_t)REC_T(u3) * 32 + li];
            u0 = ld_rec_nt(recs + p + 4);
            u1 = ld_rec_nt(recs + p + 5);
            u2 = ld_rec_nt(recs + p + 6);
            u3 = ld_rec_nt(recs + p + 7);
            while (p + 12 <= e) {
                unsigned int w0 = ld_rec_nt(recs + p + 8);
                unsigned int w1 = ld_rec_nt(recs + p + 9);
                unsigned int w2 = ld_rec_nt(recs + p + 10);
                unsigned int w3 = ld_rec_nt(recs + p + 11);
                unsigned int n0 = tab32[(size_t)REC_T(u0) * 32 + li];
                unsigned int n1 = tab32[(size_t)REC_T(u1) * 32 + li];
                unsigned int n2 = tab32[(size_t)REC_T(u2) * 32 + li];
                unsigned int n3 = tab32[(size_t)REC_T(u3) * 32 + li];
                a0 += bflo(tv0); a1 += bfhi(tv0);
                a2 += bflo(tv1); a3 += bfhi(tv1);
                a0 += bflo(tv2); a1 += bfhi(tv2);
                a2 += bflo(tv3); a3 += bfhi(tv3);
                tv0 = n0; tv1 = n1; tv2 = n2; tv3 = n3;
                u0 = w0; u1 = w1; u2 = w2; u3 = w3;
                p += 4;
            }
            unsigned int n0 = tab32[(size_t)REC_T(u0) * 32 + li];
            unsigned int n1 = tab32[(size_t)REC_T(u1) * 32 + li];
            unsigned int n2 = tab32[(size_t)REC_T(u2) * 32 + li];
            unsigned int n3 = tab32[(size_t)REC_T(u3) * 32 + li];
            a0 += bflo(tv0); a1 += bfhi(tv0);
            a2 += bflo(tv1); a3 += bfhi(tv1);
            a0 += bflo(tv2); a1 += bfhi(tv2);
            a2 += bflo(tv3); a3 += bfhi(tv3);
            a0 += bflo(n0); a1 += bfhi(n0);
            a2 += bflo(n1); a3 += bfhi(n1);
            a0 += bflo(n2); a1 += bfhi(n2);
            a2 += bflo(n3); a3 += bfhi(n3);
            p += 8;
        } else if (e - p >= 4) {
            unsigned int u0 = ld_rec_nt(recs + p);
            unsigned int u1 = ld_rec_nt(recs + p + 1);
            unsigned int u2 = ld_rec_nt(recs + p + 2);
            unsigned int u3 = ld_rec_nt(recs + p + 3);
            unsigned int n0 = tab32[(size_t)REC_T(u0) * 32 + li];
            unsigned int n1 = tab32[(size_t)REC_T(u1) * 32 + li];
            unsigned int n2 = tab32[(size_t)REC_T(u2) * 32 + li];
            unsigned int n3 = tab32[(size_t)REC_T(u3) * 32 + li];
            a0 += bflo(n0); a1 += bfhi(n0);
            a2 += bflo(n1); a3 += bfhi(n1);
            a0 += bflo(n2); a1 += bfhi(n2);
            a2 += bflo(n3); a3 += bfhi(n3);
            p += 4;
        }
        for (; p < e; ++p) {
            unsigned int u = ld_rec_nt(recs + p);
            unsigned int t = tab32[(size_t)REC_T(u) * 32 + li];
            a0 += bflo(t); a1 += bfhi(t);
        }

        float alo = a0 + a2, ahi = a1 + a3;
        alo += __shfl_down(alo, 32);
        ahi += __shfl_down(ahi, 32);
        if (lane < 32) {
            sx[wave][2 * li]     = alo;
            sx[wave][2 * li + 1] = ahi;
        }
        float o = sb[lane];
        #pragma unroll
        for (int i = 0; i < H; ++i) o = fmaf(sx[wave][i], sW[i * H + lane], o);
        yout[(size_t)node * H + lane] = f2bf(o);
    }
}

// ---------------- conv layer, fully fused -------------------
template <bool LAST>
__global__ void conv_fused_k(const int* __restrict__ off, const unsigned int* __restrict__ recs,
                             const bfu* __restrict__ tab, const bfu* __restrict__ y,
                             const float* __restrict__ W_out, const float* __restrict__ b_out,
                             const float* __restrict__ W_in, const float* __restrict__ b_in,
                             bfu* __restrict__ yout, float* __restrict__ xout, int N)
{
    __shared__ unsigned int sWo[H * H / 2];
    __shared__ unsigned int sWi[H * H / 2];
    __shared__ float sbo[H], sbi[H];
    __shared__ float sx[4][H];
    int tid = threadIdx.x;
    for (int i = tid; i < H * H / 2; i += 256) {
        int i2 = i >> 6, l = i & 63;
        sWo[i] = (unsigned int)f2bf(W_out[(2 * i2) * H + l]) |
                 ((unsigned int)f2bf(W_out[(2 * i2 + 1) * H + l]) << 16);
        if (!LAST)
            sWi[i] = (unsigned int)f2bf(W_in[(2 * i2) * H + l]) |
                     ((unsigned int)f2bf(W_in[(2 * i2 + 1) * H + l]) << 16);
    }
    if (tid < H) sbo[tid] = b_out[tid];
    else if (!LAST && tid < 2 * H) sbi[tid - H] = b_in[tid - H];
    __syncthreads();

    const unsigned int* tab32 = (const unsigned int*)tab;
    const unsigned int* y32   = (const unsigned int*)y;

    int wave = tid >> 6, lane = tid & 63;
    int half = lane >> 5;
    int li   = lane & 31;

    for (int k = 0; k < 4; ++k) {
        int node = blockIdx.x * 16 + k * 4 + wave;
        if (node >= N) continue;
        int b = off[node], en = off[node + 1];
        int deg = en - b;
        int c0  = (deg + 1) >> 1;
        int p   = b + half * c0;
        int e   = (half == 0) ? (b + c0) : en;

        float a0 = 0.f, a1 = 0.f, a2 = 0.f, a3 = 0.f;

        if (e - p >= 8) {
            unsigned int u0 = ld_rec_nt(recs + p);
            unsigned int u1 = ld_rec_nt(recs + p + 1);
            unsigned int u2 = ld_rec_nt(recs + p + 2);
            unsigned int u3 = ld_rec_nt(recs + p + 3);
            unsigned int tv0 = tab32[(size_t)REC_T(u0) * 32 + li];
            unsigned int yv0 = y32[(size_t)REC_SRC(u0) * 32 + li];
            unsigned int tv1 = tab32[(size_t)REC_T(u1) * 32 + li];
            unsigned int yv1 = y32[(size_t)REC_SRC(u1) * 32 + li];
            unsigned int tv2 = tab32[(size_t)REC_T(u2) * 32 + li];
            unsigned int yv2 = y32[(size_t)REC_SRC(u2) * 32 + li];
            unsigned int tv3 = tab32[(size_t)REC_T(u3) * 32 + li];
            unsigned int yv3 = y32[(size_t)REC_SRC(u3) * 32 + li];
            u0 = ld_rec_nt(recs + p + 4);
            u1 = ld_rec_nt(recs + p + 5);
            u2 = ld_rec_nt(recs + p + 6);
            u3 = ld_rec_nt(recs + p + 7);
            while (p + 12 <= e) {
                unsigned int w0 = ld_rec_nt(recs + p + 8);
                unsigned int w1 = ld_rec_nt(recs + p + 9);
                unsigned int w2 = ld_rec_nt(recs + p + 10);
                unsigned int w3 = ld_rec_nt(recs + p + 11);
                unsigned int nt0 = tab32[(size_t)REC_T(u0) * 32 + li];
                unsigned int ny0 = y32[(size_t)REC_SRC(u0) * 32 + li];
                unsigned int nt1 = tab32[(size_t)REC_T(u1) * 32 + li];
                unsigned int ny1 = y32[(size_t)REC_SRC(u1) * 32 + li];
                unsigned int nt2 = tab32[(size_t)REC_T(u2) * 32 + li];
                unsigned int ny2 = y32[(size_t)REC_SRC(u2) * 32 + li];
                unsigned int nt3 = tab32[(size_t)REC_T(u3) * 32 + li];
                unsigned int ny3 = y32[(size_t)REC_SRC(u3) * 32 + li];
                a0 = fmaf(bflo(yv0), bflo(tv0), a0);
                a1 = fmaf(bfhi(yv0), bfhi(tv0), a1);
                a2 = fmaf(bflo(yv1), bflo(tv1), a2);
                a3 = fmaf(bfhi(yv1), bfhi(tv1), a3);
                a0 = fmaf(bflo(yv2), bflo(tv2), a0);
                a1 = fmaf(bfhi(yv2), bfhi(tv2), a1);
                a2 = fmaf(bflo(yv3), bflo(tv3), a2);
                a3 = fmaf(bfhi(yv3), bfhi(tv3), a3);
                tv0 = nt0; yv0 = ny0; tv1 = nt1; yv1 = ny1;
                tv2 = nt2; yv2 = ny2; tv3 = nt3; yv3 = ny3;
                u0 = w0; u1 = w1; u2 = w2; u3 = w3;
                p += 4;
            }
            unsigned int nt0 = tab32[(size_t)REC_T(u0) * 32 + li];
            unsigned int ny0 = y32[(size_t)REC_SRC(u0) * 32 + li];
            unsigned int nt1 = tab32[(size_t)REC_T(u1) * 32 + li];
            unsigned int ny1 = y32[(size_t)REC_SRC(u1) * 32 + li];
            unsigned int nt2 = tab32[(size_t)REC_T(u2) * 32 + li];
            unsigned int ny2 = y32[(size_t)REC_SRC(u2) * 32 + li];
            unsigned int nt3 = tab32[(size_t)REC_T(u3) * 32 + li];
            unsigned int ny3 = y32[(size_t)REC_SRC(u3) * 32 + li];
            a0 = fmaf(bflo(yv0), bflo(tv0), a0);
            a1 = fmaf(bfhi(yv0), bfhi(tv0), a1);
            a2 = fmaf(bflo(yv1), bflo(tv1), a2);
            a3 = fmaf(bfhi(yv1), bfhi(tv1), a3);
            a0 = fmaf(bflo(yv2), bflo(tv2), a0);
            a1 = fmaf(bfhi(yv2), bfhi(tv2), a1);
            a2 = fmaf(bflo(yv3), bflo(tv3), a2);
            a3 = fmaf(bfhi(yv3), bfhi(tv3), a3);
            a0 = fmaf(bflo(ny0), bflo(nt0), a0);
            a1 = fmaf(bfhi(ny0), bfhi(nt0), a1);
            a2 = fmaf(bflo(ny1), bflo(nt1), a2);
            a3 = fmaf(bfhi(ny1), bfhi(nt1), a3);
            a0 = fmaf(bflo(ny2), bflo(nt2), a0);
            a1 = fmaf(bfhi(ny2), bfhi(nt2), a1);
            a2 = fmaf(bflo(ny3), bflo(nt3), a2);
            a3 = fmaf(bfhi(ny3), bfhi(nt3), a3);
            p += 8;
        } else if (e - p >= 4) {
            unsigned int u0 = ld_rec_nt(recs + p);
            unsigned int u1 = ld_rec_nt(recs + p + 1);
            unsigned int u2 = ld_rec_nt(recs + p + 2);
            unsigned int u3 = ld_rec_nt(recs + p + 3);
            unsigned int nt0 = tab32[(size_t)REC_T(u0) * 32 + li];
            unsigned int ny0 = y32[(size_t)REC_SRC(u0) * 32 + li];
            unsigned int nt1 = tab32[(size_t)REC_T(u1) * 32 + li];
            unsigned int ny1 = y32[(size_t)REC_SRC(u1) * 32 + li];
            unsigned int nt2 = tab32[(size_t)REC_T(u2) * 32 + li];
            unsigned int ny2 = y32[(size_t)REC_SRC(u2) * 32 + li];
            unsigned int nt3 = tab32[(size_t)REC_T(u3) * 32 + li];
            unsigned int ny3 = y32[(size_t)REC_SRC(u3) * 32 + li];
            a0 = fmaf(bflo(ny0), bflo(nt0), a0);
            a1 = fmaf(bfhi(ny0), bfhi(nt0), a1);
            a2 = fmaf(bflo(ny1), bflo(nt1), a2);
            a3 = fmaf(bfhi(ny1), bfhi(nt1), a3);
            a0 = fmaf(bflo(ny2), bflo(nt2), a0);
            a1 = fmaf(bfhi(ny2), bfhi(nt2), a1);
            a2 = fmaf(bflo(ny3), bflo(nt3), a2);
            a3 = fmaf(bfhi(ny3), bfhi(nt3), a3);
            p += 4;
        }
        for (; p < e; ++p) {
            unsigned int u = ld_rec_nt(recs + p);
            unsigned int t = tab32[(size_t)REC_T(u) * 32 + li];
            unsigned int v = y32[(size_t)REC_SRC(u) * 32 + li];
            a0 = fmaf(bflo(v), bflo(t), a0);
            a1 = fmaf(bfhi(v), bfhi(t), a1);
        }

        float alo = a0 + a2, ahi = a1 + a3;
        alo += __shfl_down(alo, 32);
        ahi += __shfl_down(ahi, 32);
        if (lane < 32) {
            sx[wave][2 * li]     = alo;
            sx[wave][2 * li + 1] = ahi;
        }
        float o = sbo[lane];
        #pragma unroll
        for (int i2 = 0; i2 < H / 2; ++i2) {
            unsigned int u = sWo[i2 * H + lane];
            o = fmaf(sx[wave][2 * i2],     bflo(u), o);
            o = fmaf(sx[wave][2 * i2 + 1], bfhi(u), o);
        }
        o = fmaxf(o, 0.f);
        if (LAST) {
            xout[(size_t)node * H + lane] = o;
        } else {
            sx[wave][lane] = o;   // same-wave reuse: prior reads are complete
            float o2 = sbi[lane];
            #pragma unroll
            for (int i2 = 0; i2 < H / 2; ++i2) {
                unsigned int u = sWi[i2 * H + lane];
                o2 = fmaf(sx[wave][2 * i2],     bflo(u), o2);
                o2 = fmaf(sx[wave][2 * i2 + 1], bfhi(u), o2);
            }
            yout[(size_t)node * H + lane] = f2bf(o2);
        }
    }
}

// ---------------- pooling (sorted gid, run-length flush) -------------------
__global__ void pool_kernel(const float* __restrict__ x, const int* __restrict__ gid,
                            float* __restrict__ pooled, float* __restrict__ counts, int N)
{
    int wavesPerBlock = blockDim.x >> 6;
    int wid  = blockIdx.x * wavesPerBlock + (threadIdx.x >> 6);
    int lane = threadIdx.x & 63;
    int totalWaves = gridDim.x * wavesPerBlock;
    int chunk = (N + totalWaves - 1) / totalWaves;
    int beg = wid * chunk, end = min(beg + chunk, N);
    if (beg >= end) return;

    float acc = 0.f;
    int cur = -1, cnt = 0;
    for (int n = beg; n < end; ++n) {
        int g = gid[n];
        if (g != cur) {
            if (cur >= 0) {
                atomicAdd(&pooled[(size_t)cur * H + lane], acc);
                if (lane == 0) atomicAdd(&counts[cur], (float)cnt);
            }
            cur = g; acc = 0.f; cnt = 0;
        }
        acc += x[(size_t)n * H + lane];
        cnt++;
    }
    atomicAdd(&pooled[(size_t)cur * H + lane], acc);
    if (lane == 0) atomicAdd(&counts[cur], (float)cnt);
}

// ---------------- head -------------------
__global__ void head_kernel(const float* __restrict__ pooled, const float* __restrict__ counts,
                            const float* __restrict__ Wfc, const float* __restrict__ bfc,
                            float* __restrict__ out)
{
    int g = blockIdx.x;
    int c = threadIdx.x;
    __shared__ float logits[NCLASSES];
    float cnt = fmaxf(counts[g], 1.0f);
    if (c < NCLASSES) {
        float acc = bfc[c];
        #pragma unroll
        for (int i = 0; i < H; ++i)
            acc = fmaf(pooled[(size_t)g * H + i] / cnt, Wfc[i * NCLASSES + c], acc);
        logits[c] = acc;
    }
    __syncthreads();
    if (c < NCLASSES) {
        float m = -INFINITY;
        #pragma unroll
        for (int k = 0; k < NCLASSES; ++k) m = fmaxf(m, logits[k]);
        float s = 0.f;
        #pragma unroll
        for (int k = 0; k < NCLASSES; ++k) s += expf(logits[k] - m);
        out[g * NCLASSES + c] = logits[c] - m - logf(s);
    }
}

extern "C" void kernel_launch(void* const* d_in, const int* in_sizes, int n_in,
                              void* d_out, int out_size, void* d_ws, size_t ws_size,
                              hipStream_t stream)
{
    const float* d_d    = (const float*)d_in[0];
    const float* W_emb1 = (const float*)d_in[1];
    const float* b_emb1 = (const float*)d_in[2];
    const float* W_emb2 = (const float*)d_in[3];
    const float* b_emb2 = (const float*)d_in[4];
    const float* fW1    = (const float*)d_in[5];
    const float* fb1    = (const float*)d_in[6];
    const float* fW2    = (const float*)d_in[7];
    const float* fb2    = (const float*)d_in[8];
    const float* W_in   = (const float*)d_in[9];
    const float* b_in   = (const float*)d_in[10];
    const float* W_out  = (const float*)d_in[11];
    const float* b_out  = (const float*)d_in[12];
    const float* W_fc   = (const float*)d_in[13];
    const float* b_fc   = (const float*)d_in[14];
    const int*   src    = (const int*)d_in[15];
    const int*   dst    = (const int*)d_in[16];
    const int*   gid    = (const int*)d_in[17];

    const int E = in_sizes[0];
    const int N = in_sizes[17];
    const int ncb = (N + 255) >> 8;   // coarse buckets (<= 256)

    float* out = (float*)d_out;

    // workspace layout (x3 and cbuf share a union region — disjoint lifetimes)
    char* base = (char*)d_ws;
    unsigned int* recs = (unsigned int*)base;   base += (size_t)E * 4;
    bfu*  tabs   = (bfu*)base;                  base += (size_t)4 * TROWS * H * 2;
    bfu*  yA     = (bfu*)base;                  base += (size_t)N * H * 2;
    bfu*  yB     = (bfu*)base;                  base += (size_t)N * H * 2;
    size_t usz   = (size_t)N * H * 4;
    size_t csz   = (size_t)ncb * CAP * 8;
    char* uni    = base;                        base += (usz > csz ? usz : csz);
    float* x3    = (float*)uni;
    unsigned long long* cbuf = (unsigned long long*)uni;
    float* pooled= (float*)base;                base += (size_t)NGRAPHS * H * 4;
    float* counts= (float*)base;                base += (size_t)NGRAPHS * 4;
    int*  off    = (int*)base;                  base += (size_t)(N + 1) * 4;
    int*  ccur   = (int*)base;                  base += 256 * 4;
    int*  cstart = (int*)base;                  base += 256 * 4;

    const int node_blocks16 = (N + 15) / 16;
    const int part_blocks   = (E + 256 * EPT - 1) / (256 * EPT);

    // 1. bf16 MLP lookup tables
    dim3 tg((TROWS + 63) / 64, 4);
    build_tables<<<tg, 256, 0, stream>>>(W_emb1, b_emb1, W_emb2, b_emb2,
                                         fW1, fb1, fW2, fb2, tabs);

    // 2. CSR build: two-level LDS counting sort (no mass device atomics)
    hipMemsetAsync(ccur, 0, 256 * 4, stream);
    coarse_part<<<part_blocks, 256, 0, stream>>>(src, dst, d_d, ccur, cbuf, E, ncb);
    cscan<<<1, 256, 0, stream>>>(ccur, cstart, off, E, N, ncb);
    fine_sort<<<ncb, 256, 0, stream>>>(cbuf, ccur, cstart, off, recs, N);

    // 3. embedding + W_in0 -> yA
    emb_fused<<<node_blocks16, 256, 0, stream>>>(off, recs, tabs, W_in, b_in, yA, N);

    // 4. conv layers, fully fused (out-proj + next in-proj in epilogue)
    conv_fused_k<false><<<node_blocks16, 256, 0, stream>>>(
        off, recs, tabs + (size_t)1 * TROWS * H, yA,
        W_out, b_out, W_in + (size_t)1 * H * H, b_in + (size_t)1 * H, yB, nullptr, N);
    conv_fused_k<false><<<node_blocks16, 256, 0, stream>>>(
        off, recs, tabs + (size_t)2 * TROWS * H, yB,
        W_out + (size_t)1 * H * H, b_out + (size_t)1 * H,
        W_in + (size_t)2 * H * H, b_in + (size_t)2 * H, yA, nullptr, N);
    conv_fused_k<true><<<node_blocks16, 256, 0, stream>>>(
        off, recs, tabs + (size_t)3 * TROWS * H, yA,
        W_out + (size_t)2 * H * H, b_out + (size_t)2 * H,
        nullptr, nullptr, nullptr, x3, N);

    // 5. pooling
    hipMemsetAsync(pooled, 0, ((size_t)NGRAPHS * H + NGRAPHS) * 4, stream);
    pool_kernel<<<128, 256, 0, stream>>>(x3, gid, pooled, counts, N);

    // 6. head
    head_kernel<<<NGRAPHS, 64, 0, stream>>>(pooled, counts, W_fc, b_fc, out);
}